// Round 6
// baseline (433.721 us; speedup 1.0000x reference)
//
#include <hip/hip_runtime.h>
#include <math.h>

#define IMSIZE 64
#define S_SIZE 4096
#define A_SZ 8
#define C_SZ 10
#define B_SIZE 32
#define SB 128
#define VI_K 30
#define GAMMA 0.99f
#define NBLK 256
#define NTHR 512

// v layout (global + LDS): [g][s*8 + b8]  (32 B per state row -> b128 gathers)

__global__ void zero_bar(int* bar) {
    if (threadIdx.x < 32) bar[threadIdx.x] = 0;
}

__device__ __forceinline__ float conv_at(const float* __restrict__ x,
                                         const float* __restrict__ cw,
                                         float cb, int b, int s) {
    int y = s >> 6, xx = s & 63;
    float acc = cb;
#pragma unroll
    for (int ic = 0; ic < 2; ++ic) {
        const float* xp = x + ((b * 2 + ic) << 12);
#pragma unroll
        for (int ky = 0; ky < 3; ++ky) {
            int yy = y + ky - 1;
            if (yy < 0 || yy >= IMSIZE) continue;
#pragma unroll
            for (int kx = 0; kx < 3; ++kx) {
                int xc = xx + kx - 1;
                if (xc < 0 || xc >= IMSIZE) continue;
                acc = fmaf(xp[(yy << 6) + xc], cw[(ic * 3 + ky) * 3 + kx], acc);
            }
        }
    }
    return acc;
}

// inter-block barrier: one release-add + acquire-spin per block, slot per iter
__device__ __forceinline__ void gbar(int* bar, int slot, int tid) {
    __syncthreads();                    // drain this block's stores (vmcnt 0)
    if (tid == 0) {
        __hip_atomic_fetch_add(&bar[slot], 1, __ATOMIC_RELEASE,
                               __HIP_MEMORY_SCOPE_AGENT);
        while (__hip_atomic_load(&bar[slot], __ATOMIC_ACQUIRE,
                                 __HIP_MEMORY_SCOPE_AGENT) != NBLK)
            __builtin_amdgcn_s_sleep(2);
    }
    __syncthreads();
}

// grid = 256 blocks (blockIdx = slice*4 + g), block = 512 thr = (w<<3)|a.
// Block (slice,g): batch group g (8 batches), states slice*64..+64.
// LDS holds the group's full v [s*8+b8] (128 KiB, 1 block/CU).
__global__ __launch_bounds__(NTHR) void vin_full(
    const float* __restrict__ x,
    const int* __restrict__ s1,
    const int* __restrict__ s2,
    const int* __restrict__ ds_state,
    const int* __restrict__ ds_prob,
    const float* __restrict__ conv_w,
    const float* __restrict__ conv_b,
    const float* __restrict__ pv,
    const float* __restrict__ lin_w,
    const float* __restrict__ lin_b,
    float* __restrict__ vA,
    float* __restrict__ vB,
    int* __restrict__ bar,
    float* __restrict__ out)
{
    __shared__ float vld[8 * S_SIZE];   // 128 KiB
    const int g = blockIdx.x & 3;
    const int slice = blockIdx.x >> 2;
    const int tid = threadIdx.x;

    // ---- phase 0: conv init in (w0,b80) roles, exchange through LDS ----
    {
        int w0 = tid >> 3, b80 = tid & 7;
        int s0 = (slice << 6) + w0;
        int b0 = (g << 3) + b80;
        float sar0 = conv_at(x, conv_w, conv_b[0], b0, s0);
        float x1 = x[((b0 * 2 + 1) << 12) + s0];
        float coef0 = GAMMA * (1.0f - 0.1f * x1);
        vld[(unsigned)tid * 2]     = sar0;
        vld[(unsigned)tid * 2 + 1] = coef0;
        // publish v0 (= sar) at coherence point
        atomicExch(&vA[(g << 15) + (s0 << 3) + b80], sar0);
    }
    __syncthreads();

    // ---- (w,a) roles: persistent registers for all 29 iterations ----
    const int w = tid >> 3, a = tid & 7;
    const int s = (slice << 6) + w;
    float sar_r[8], coef_r[8];
#pragma unroll
    for (int b = 0; b < 8; ++b) {
        sar_r[b]  = vld[(unsigned)(w * 8 + b) * 2];
        coef_r[b] = vld[(unsigned)(w * 8 + b) * 2 + 1];
    }
    int   off_r[C_SZ];
    float pr_r[C_SZ];
    {
        const int base_sa = (s * A_SZ + a) * C_SZ;
#pragma unroll
        for (int c = 0; c < C_SZ; ++c)
            off_r[c] = ds_state[base_sa + c] << 5;   // byte offset of state row
#pragma unroll
        for (int c = 0; c < C_SZ; ++c) {
            float p = pv[ds_prob[base_sa + c]];
            pr_r[c] = fminf(fmaxf(p, 0.0f), 1.0f);
        }
    }
    gbar(bar, 0, tid);

    // ---- 29 value-iteration steps, all in one dispatch ----
    const float* vi_p = vA;
    float*       vo_p = vB;
    for (int k = 0; k < VI_K - 1; ++k) {
        // stage group v: 8192 float4, global -> LDS direct
        const float4* src4 = (const float4*)(vi_p + (g << 15));
        float4* dst4 = (float4*)vld;
#if __has_builtin(__builtin_amdgcn_global_load_lds)
#pragma unroll
        for (int r = 0; r < 16; ++r) {
            int i = tid + (r << 9);
            __builtin_amdgcn_global_load_lds(
                (const __attribute__((address_space(1))) void*)(src4 + i),
                (__attribute__((address_space(3))) void*)(dst4 + i), 16, 0, 0);
        }
#else
#pragma unroll
        for (int r = 0; r < 16; ++r) {
            int i = tid + (r << 9);
            dst4[i] = src4[i];
        }
#endif
        __syncthreads();

        // gather-accumulate: 10 entries x 2 b128 (8 batches each)
        float4 acc_lo = {0.f, 0.f, 0.f, 0.f};
        float4 acc_hi = {0.f, 0.f, 0.f, 0.f};
        const char* vbase = (const char*)vld;
#pragma unroll
        for (int c = 0; c < C_SZ; ++c) {
            float p = pr_r[c];
            float4 lo = *(const float4*)(vbase + off_r[c]);
            float4 hi = *(const float4*)(vbase + off_r[c] + 16);
            acc_lo.x = fmaf(p, lo.x, acc_lo.x); acc_lo.y = fmaf(p, lo.y, acc_lo.y);
            acc_lo.z = fmaf(p, lo.z, acc_lo.z); acc_lo.w = fmaf(p, lo.w, acc_lo.w);
            acc_hi.x = fmaf(p, hi.x, acc_hi.x); acc_hi.y = fmaf(p, hi.y, acc_hi.y);
            acc_hi.z = fmaf(p, hi.z, acc_hi.z); acc_hi.w = fmaf(p, hi.w, acc_hi.w);
        }

        float q[8];
        q[0] = fmaf(coef_r[0], acc_lo.x, sar_r[0]);
        q[1] = fmaf(coef_r[1], acc_lo.y, sar_r[1]);
        q[2] = fmaf(coef_r[2], acc_lo.z, sar_r[2]);
        q[3] = fmaf(coef_r[3], acc_lo.w, sar_r[3]);
        q[4] = fmaf(coef_r[4], acc_hi.x, sar_r[4]);
        q[5] = fmaf(coef_r[5], acc_hi.y, sar_r[5]);
        q[6] = fmaf(coef_r[6], acc_hi.z, sar_r[6]);
        q[7] = fmaf(coef_r[7], acc_hi.w, sar_r[7]);

        // max over the 8 action-lanes (butterfly, width 8)
#pragma unroll
        for (int offs = 1; offs < 8; offs <<= 1) {
#pragma unroll
            for (int b = 0; b < 8; ++b)
                q[b] = fmaxf(q[b], __shfl_xor(q[b], offs, 8));
        }
        float myv = q[0];
#pragma unroll
        for (int b = 1; b < 8; ++b)
            if (a == b) myv = q[b];
        // publish at coherence point (no dirty L2 -> cheap release)
        atomicExch(&vo_p[(g << 15) + (s << 3) + a], myv);

        gbar(bar, k + 1, tid);

        float* tmp = (float*)vi_p; vi_p = vo_p; vo_p = tmp;
    }

    // ---- stage v29 and compute this block's 16 outputs ----
    {
        const float4* src4 = (const float4*)(vi_p + (g << 15));
        float4* dst4 = (float4*)vld;
#if __has_builtin(__builtin_amdgcn_global_load_lds)
#pragma unroll
        for (int r = 0; r < 16; ++r) {
            int i = tid + (r << 9);
            __builtin_amdgcn_global_load_lds(
                (const __attribute__((address_space(1))) void*)(src4 + i),
                (__attribute__((address_space(3))) void*)(dst4 + i), 16, 0, 0);
        }
#else
#pragma unroll
        for (int r = 0; r < 16; ++r) {
            int i = tid + (r << 9);
            dst4[i] = src4[i];
        }
#endif
    }
    __syncthreads();

    if (tid < 16) {
        int b8 = tid >> 1;
        int b  = (g << 3) + b8;
        int j  = (slice << 1) + (tid & 1);
        int t2 = b * SB + j;
        int ss = s1[t2] * IMSIZE + s2[t2];

        float sar = conv_at(x, conv_w, conv_b[0], b, ss);
        float x1 = x[((b * 2 + 1) << 12) + ss];
        float coef = GAMMA * (1.0f - 0.1f * x1);

        float q[A_SZ];
#pragma unroll
        for (int a2 = 0; a2 < A_SZ; ++a2) {
            float accq = 0.0f;
            int bb = (ss * A_SZ + a2) * C_SZ;
#pragma unroll
            for (int c = 0; c < C_SZ; ++c) {
                float p = pv[ds_prob[bb + c]];
                p = fminf(fmaxf(p, 0.0f), 1.0f);
                accq = fmaf(p, vld[(ds_state[bb + c] << 3) + b8], accq);
            }
            q[a2] = fmaf(coef, accq, sar);
        }
#pragma unroll
        for (int i = 0; i < A_SZ; ++i) {
            float o = lin_b[i] + q[i];
#pragma unroll
            for (int a2 = 0; a2 < A_SZ; ++a2)
                o = fmaf(q[a2], lin_w[i * 8 + a2], o);
            out[t2 * 8 + i] = o;
        }
    }
}

extern "C" void kernel_launch(void* const* d_in, const int* in_sizes, int n_in,
                              void* d_out, int out_size, void* d_ws, size_t ws_size,
                              hipStream_t stream) {
    const float* x        = (const float*)d_in[0];
    const int*   s1       = (const int*)d_in[1];
    const int*   s2       = (const int*)d_in[2];
    const int*   ds_state = (const int*)d_in[3];
    const int*   ds_prob  = (const int*)d_in[4];
    const float* conv_w   = (const float*)d_in[5];
    const float* conv_b   = (const float*)d_in[6];
    const float* pv       = (const float*)d_in[7];
    const float* lin_w    = (const float*)d_in[8];
    const float* lin_b    = (const float*)d_in[9];
    float* out = (float*)d_out;

    const size_t VSZ = (size_t)B_SIZE * S_SIZE * 4;   // 512 KiB
    char* ws = (char*)d_ws;
    float* vA  = (float*)(ws);
    float* vB  = (float*)(ws + VSZ);
    int*   bar = (int*)(ws + 2 * VSZ);

    zero_bar<<<1, 64, 0, stream>>>(bar);

    void* args[] = {
        (void*)&x, (void*)&s1, (void*)&s2, (void*)&ds_state, (void*)&ds_prob,
        (void*)&conv_w, (void*)&conv_b, (void*)&pv, (void*)&lin_w, (void*)&lin_b,
        (void*)&vA, (void*)&vB, (void*)&bar, (void*)&out
    };
    hipLaunchCooperativeKernel((void*)vin_full, dim3(NBLK), dim3(NTHR),
                               args, 0, stream);
}